// Round 8
// baseline (137.803 us; speedup 1.0000x reference)
//
#include <hip/hip_runtime.h>

// 5-level Db4 DWT, rows of 16384 fp32, B*C = 4096 rows.
// Fused-composite structure: a2,d2 computed DIRECTLY from x via 22-tap
// composite filters (levels 1+2 fused, stride 4); a4,d4 from a2 the same way
// (levels 3+4 fused); d3 = plain 8-tap on a2; level 5 = plain 8-tap on a4.
// Only a2 (4.3KB) and a4 (1.2KB) ever touch LDS -> 2 barriers, 8 blocks/CU.
// Rows split into 4 quarter-blocks with low-pass halos (a2:56, a4:8).
// out layout (flat, return order):
//   Fd  4096x512   @ 0
//   Ft  4096x512   @ 2097152
//   Fa  4096x1024  @ 4194304
//   Fb  4096x2048  @ 8388608
//   Fg  4096x4096  @ 16777216
//   FR  4096x8192  @ 33554432   (per-row: [Fd|Ft|Fa|Fb|Fg])

static constexpr int SLEN = 16384;
typedef float f32x4 __attribute__((ext_vector_type(4)));

constexpr double Hd[8] = {-0.010597401785069032, 0.032883011666982945, 0.030841381835560764,
                          -0.18703481171888114, -0.02798376941698385, 0.6308807679295904,
                          0.7148465705529155, 0.2303778133088964};
// g[k] = (-1)^k * h[7-k]
constexpr double Gd[8] = { 0.2303778133088964, -0.7148465705529155, 0.6308807679295904,
                           0.02798376941698385, -0.18703481171888114, -0.030841381835560764,
                           0.032883011666982945, 0.010597401785069032};

// Composite (outer at level L+1, inner at level L): c[i] = sum_{2j+k=i} o[j]*in[k]
struct C22 { float c[22]; };
constexpr C22 comp22(const double* o, const double* in) {
    C22 r{};
    double acc[22] = {};
    for (int j = 0; j < 8; ++j)
        for (int k = 0; k < 8; ++k)
            acc[2*j + k] += o[j] * in[k];
    for (int i = 0; i < 22; ++i) r.c[i] = (float)acc[i];
    return r;
}
constexpr C22 CLL = comp22(Hd, Hd);   // low  composite: a_{l+2}[n] = sum c[i]*src[4n-21+i]
constexpr C22 CHL = comp22(Gd, Hd);   // high composite: d_{l+2}[n]

// LDS slot swizzle: slot' = slot ^ ((slot>>3)&7), within 32-float groups.
__device__ __forceinline__ int swz4(int f) {
    const int s = f >> 2;
    return (s ^ ((s >> 3) & 7)) << 2;
}
__device__ __forceinline__ int swz1(int f) {
    const int s = f >> 2;
    return (((s ^ ((s >> 3) & 7)) << 2) | (f & 3));
}

__device__ __forceinline__ float dotH(const float* w) {
    float s =      -0.010597401785069032f * w[0];
    s = fmaf( 0.032883011666982945f, w[1], s);
    s = fmaf( 0.030841381835560764f, w[2], s);
    s = fmaf(-0.18703481171888114f,  w[3], s);
    s = fmaf(-0.02798376941698385f,  w[4], s);
    s = fmaf( 0.6308807679295904f,   w[5], s);
    s = fmaf( 0.7148465705529155f,   w[6], s);
    s = fmaf( 0.2303778133088964f,   w[7], s);
    return s;
}
__device__ __forceinline__ float dotG(const float* w) {
    float s =       0.2303778133088964f * w[0];
    s = fmaf(-0.7148465705529155f,   w[1], s);
    s = fmaf( 0.6308807679295904f,   w[2], s);
    s = fmaf( 0.02798376941698385f,  w[3], s);
    s = fmaf(-0.18703481171888114f,  w[4], s);
    s = fmaf(-0.030841381835560764f, w[5], s);
    s = fmaf( 0.032883011666982945f, w[6], s);
    s = fmaf( 0.010597401785069032f, w[7], s);
    return s;
}

// Composite over a 40-float window (10 float4), outputs t=0..3:
// out[t] = sum_i c[i] * w[4t+3+i]
#define COMP_BODY(LOADEXPR)                                              \
    _Pragma("unroll")                                                    \
    for (int t = 0; t < 4; ++t) { accA[t] = 0.f; accD[t] = 0.f; }        \
    _Pragma("unroll")                                                    \
    for (int s = 0; s < 10; ++s) {                                       \
        const float4 v = (LOADEXPR);                                     \
        const float ve[4] = {v.x, v.y, v.z, v.w};                        \
        _Pragma("unroll")                                                \
        for (int e = 0; e < 4; ++e) {                                    \
            _Pragma("unroll")                                            \
            for (int t = 0; t < 4; ++t) {                                \
                const int i = 4*s + e - 4*t - 3;                         \
                if (i >= 0 && i < 22) {                                  \
                    accA[t] = fmaf(CLL.c[i], ve[e], accA[t]);            \
                    accD[t] = fmaf(CHL.c[i], ve[e], accD[t]);            \
                }                                                        \
            }                                                            \
        }                                                                \
    }

__device__ __forceinline__ void comp4g(const float* __restrict__ wp,
                                       float* accA, float* accD) {
    COMP_BODY(*(const float4*)(wp + 4*s))
}
__device__ __forceinline__ void comp4l(const float* __restrict__ base, int rel,
                                       float* accA, float* accD) {
    COMP_BODY(*(const float4*)(base + swz4(rel + 4*s)))
}

// Boundary (qd==0, group Q in {0,1}): explicit 2-level cascade with reflect.
// Level pair from global x.
template<int Q>
__device__ __forceinline__ void bndA2(const float* __restrict__ xr,
                                      float* accA, float* accD) {
    float a1v[15];
#pragma unroll
    for (int m = 0; m < 15; ++m) {
        float s = 0.f;
#pragma unroll
        for (int k = 0; k < 8; ++k) {
            int ix = 2*m + k - 7; ix = ix < 0 ? -ix : ix;
            s = fmaf((float)Hd[k], xr[ix], s);
        }
        a1v[m] = s;
    }
#pragma unroll
    for (int t = 0; t < 4; ++t) {
        float sa = 0.f, sd = 0.f;
#pragma unroll
        for (int j = 0; j < 8; ++j) {
            int ix = 2*(4*Q + t) + j - 7; ix = ix < 0 ? -ix : ix;
            const float v = a1v[ix];
            sa = fmaf((float)Hd[j], v, sa);
            sd = fmaf((float)Gd[j], v, sd);
        }
        accA[t] = sa; accD[t] = sd;
    }
}
// Level pair from a2 in LDS (swizzled, region-relative == global for qd==0).
template<int P>
__device__ __forceinline__ void bndA4(const float* __restrict__ a2b,
                                      float* accA, float* accD) {
    float a3v[15];
#pragma unroll
    for (int m = 0; m < 15; ++m) {
        float s = 0.f;
#pragma unroll
        for (int k = 0; k < 8; ++k) {
            int ix = 2*m + k - 7; ix = ix < 0 ? -ix : ix;
            s = fmaf((float)Hd[k], a2b[swz1(ix)], s);
        }
        a3v[m] = s;
    }
#pragma unroll
    for (int t = 0; t < 4; ++t) {
        float sa = 0.f, sd = 0.f;
#pragma unroll
        for (int j = 0; j < 8; ++j) {
            int ix = 2*(4*P + t) + j - 7; ix = ix < 0 ? -ix : ix;
            const float v = a3v[ix];
            sa = fmaf((float)Hd[j], v, sa);
            sd = fmaf((float)Gd[j], v, sd);
        }
        accA[t] = sa; accD[t] = sd;
    }
}

// Single-level swizzled LDS window load (16 floats from region-rel foff).
__device__ __forceinline__ void lw16s(const float* __restrict__ base, int foff, float* w) {
#pragma unroll
    for (int j = 0; j < 4; ++j) {
        const float4 v = *(const float4*)(base + swz4(foff + 4*j));
        w[4*j+0] = v.x; w[4*j+1] = v.y; w[4*j+2] = v.z; w[4*j+3] = v.w;
    }
}
__device__ __forceinline__ void lw16s_q0(const float* __restrict__ base, float* w) {
#pragma unroll
    for (int i = 0; i < 16; ++i) { int m = i - 8; m = (m < 0) ? -m : m; w[i] = base[swz1(m)]; }
}

__device__ __forceinline__ void ntst4(float* p, float a0, float a1, float a2, float a3) {
    f32x4 v; v.x = a0; v.y = a1; v.z = a2; v.w = a3;
    __builtin_nontemporal_store(v, (f32x4*)p);
}

__device__ __forceinline__ void barrier_lds() {
    asm volatile("s_waitcnt lgkmcnt(0)" ::: "memory");
    __builtin_amdgcn_s_barrier();
    asm volatile("" ::: "memory");
}

__global__ __launch_bounds__(256, 8)
void dwt5_kernel(const float* __restrict__ x, float* __restrict__ out)
{
    __shared__ float buf[1376];          // a2: [0..1088), a4: [1088..1376)
    float* const a2b = buf;
    float* const a4b = buf + 1088;

    const int bid = blockIdx.x;
    const int r   = bid >> 2;            // row
    const int qd  = bid & 3;             // quarter
    const int tid = threadIdx.x;

    const float* __restrict__ xr = x + (size_t)r * SLEN;
    const size_t frBase = (size_t)33554432 + (size_t)r * 8192;

    const int A2s = qd ? 1024*qd - 56 : 0;   // a2 region global start (floats)
    const int A4s = qd ? 256*qd  - 8  : 0;   // a4 region global start

    // ---- Phase 1: x -> a2 (LDS) + d2 -> Fg+FR  (levels 1+2 fused) ----
    {
        float* __restrict__ hi1 = out + (size_t)16777216 + (size_t)r * 4096;
        float* __restrict__ hi2 = out + frBase + 4096;
        const int q0  = A2s >> 2;
        const int qhi = 256*(qd+1);
        const int gd  = 256*qd;
#pragma unroll
        for (int jj = 0; jj < 2; ++jj) {
            const int q = q0 + tid + jj*256;
            if (q < qhi) {
                float accA[4], accD[4];
                if (qd == 0 && q < 2) {
                    if (q == 0) bndA2<0>(xr, accA, accD);
                    else        bndA2<1>(xr, accA, accD);
                } else {
                    comp4g(xr + 16*q - 24, accA, accD);
                }
                *(float4*)(a2b + swz4(4*q - A2s)) =
                    make_float4(accA[0], accA[1], accA[2], accA[3]);
                if (q >= gd) {
                    ntst4(hi1 + 4*q, accD[0], accD[1], accD[2], accD[3]);
                    ntst4(hi2 + 4*q, accD[0], accD[1], accD[2], accD[3]);
                }
            }
        }
    }
    barrier_lds();

    // ---- Phase 2: (a) d3 from a2 -> Fb+FR; (b) a2 -> a4 (LDS) + d4 -> Fa+FR ----
    {
        if (tid < 128) {
            const int p = 128*qd + tid;
            float* __restrict__ hi1 = out + (size_t)8388608 + (size_t)r * 2048;
            float* __restrict__ hi2 = out + frBase + 2048;
            float w[16];
            if (p == 0) lw16s_q0(a2b, w);
            else        lw16s(a2b, 8*p - 8 - A2s, w);
            const float d0 = dotG(w+1), d1 = dotG(w+3), d2 = dotG(w+5), d3 = dotG(w+7);
            ntst4(hi1 + 4*p, d0, d1, d2, d3);
            ntst4(hi2 + 4*p, d0, d1, d2, d3);
        } else {
            const int t2  = tid - 128;
            const int p   = (A4s >> 2) + t2;
            const int phi = 64*(qd+1);
            if (p < phi) {
                float accA[4], accD[4];
                if (qd == 0 && p < 2) {
                    if (p == 0) bndA4<0>(a2b, accA, accD);
                    else        bndA4<1>(a2b, accA, accD);
                } else {
                    comp4l(a2b, 16*p - 24 - A2s, accA, accD);
                }
                *(float4*)(a4b + swz4(4*p - A4s)) =
                    make_float4(accA[0], accA[1], accA[2], accA[3]);
                if (p >= 64*qd) {
                    float* __restrict__ hi1 = out + (size_t)4194304 + (size_t)r * 1024;
                    float* __restrict__ hi2 = out + frBase + 1024;
                    ntst4(hi1 + 4*p, accD[0], accD[1], accD[2], accD[3]);
                    ntst4(hi2 + 4*p, accD[0], accD[1], accD[2], accD[3]);
                }
            }
        }
    }
    barrier_lds();

    // ---- Phase 3: a4 -> Fd + Ft (+FR), plain level 5 ----
    if (tid < 32) {
        const int q5 = 32*qd + tid;
        float w[16];
        if (q5 == 0) lw16s_q0(a4b, w);
        else         lw16s(a4b, 8*q5 - 8 - A4s, w);
        const float a0 = dotH(w+1), a1 = dotH(w+3), a2v = dotH(w+5), a3v = dotH(w+7);
        const float d0 = dotG(w+1), d1 = dotG(w+3), d2v = dotG(w+5), d3v = dotG(w+7);
        ntst4(out + (size_t)r*512 + 4*q5,                   a0, a1, a2v, a3v);
        ntst4(out + frBase + 4*q5,                          a0, a1, a2v, a3v);
        ntst4(out + (size_t)2097152 + (size_t)r*512 + 4*q5, d0, d1, d2v, d3v);
        ntst4(out + frBase + 512 + 4*q5,                    d0, d1, d2v, d3v);
    }
}

extern "C" void kernel_launch(void* const* d_in, const int* in_sizes, int n_in,
                              void* d_out, int out_size, void* d_ws, size_t ws_size,
                              hipStream_t stream) {
    const float* x = (const float*)d_in[0];
    float* out = (float*)d_out;
    dwt5_kernel<<<16384, 256, 0, stream>>>(x, out);
}

// Round 9
// 86.568 us; speedup vs baseline: 1.5918x; 1.5918x over previous
//
#include <hip/hip_runtime.h>

// 5-level Db4 DWT, rows of 16384 fp32, B*C = 4096 rows.
// r7 cascade structure, but each row split across FOUR blocks (h = bid&3)
// with telescoping low-pass halos (a1:120, a2:56, a3:24, a4:8) so every
// level's first LDS window starts at region offset 0.
// LDS: disjoint per-level regions (13 KB -> 8 blocks/CU), ONE LDS-only
// barrier per level (4 total), XOR-swizzled float4 slots for conflict-free
// stride-32B window reads.
// out layout (flat, return order):
//   Fd  4096x512   @ 0
//   Ft  4096x512   @ 2097152
//   Fa  4096x1024  @ 4194304
//   Fb  4096x2048  @ 8388608
//   Fg  4096x4096  @ 16777216
//   FR  4096x8192  @ 33554432   (per-row: [Fd|Ft|Fa|Fb|Fg])

static constexpr int SLEN = 16384;

typedef float f32x4 __attribute__((ext_vector_type(4)));

// Swizzled float offset for a float4-aligned region-relative offset f (>=0).
__device__ __forceinline__ int swz4(int f) {
    const int s = f >> 2;
    return (s ^ ((s >> 3) & 7)) << 2;
}
__device__ __forceinline__ int swz1(int f) {
    const int s = f >> 2;
    return (((s ^ ((s >> 3) & 7)) << 2) | (f & 3));
}

// Db4 filters are fixed (non-learnable) — hardcoded as literals.
__device__ __forceinline__ float dotH(const float* w) {
    float s =      -0.010597401785069032f * w[0];
    s = fmaf( 0.032883011666982945f, w[1], s);
    s = fmaf( 0.030841381835560764f, w[2], s);
    s = fmaf(-0.18703481171888114f,  w[3], s);
    s = fmaf(-0.02798376941698385f,  w[4], s);
    s = fmaf( 0.6308807679295904f,   w[5], s);
    s = fmaf( 0.7148465705529155f,   w[6], s);
    s = fmaf( 0.2303778133088964f,   w[7], s);
    return s;
}
// g[k] = (-1)^k * h[7-k]
__device__ __forceinline__ float dotG(const float* w) {
    float s =       0.2303778133088964f * w[0];
    s = fmaf(-0.7148465705529155f,   w[1], s);
    s = fmaf( 0.6308807679295904f,   w[2], s);
    s = fmaf( 0.02798376941698385f,  w[3], s);
    s = fmaf(-0.18703481171888114f,  w[4], s);
    s = fmaf(-0.030841381835560764f, w[5], s);
    s = fmaf( 0.032883011666982945f, w[6], s);
    s = fmaf( 0.010597401785069032f, w[7], s);
    return s;
}

// GLOBAL window load: 16 floats x[8q-8 .. 8q+7]; q==0 reflect path.
__device__ __forceinline__ void loadw16g(const float* __restrict__ src, int q, float* w) {
    if (q == 0) {
#pragma unroll
        for (int i = 0; i < 16; ++i) { int m = i - 8; m = (m < 0) ? -m : m; w[i] = src[m]; }
    } else {
        const float4 v0 = *(const float4*)(src + 8 * q - 8);
        const float4 v1 = *(const float4*)(src + 8 * q - 4);
        const float4 v2 = *(const float4*)(src + 8 * q);
        const float4 v3 = *(const float4*)(src + 8 * q + 4);
        w[0]  = v0.x; w[1]  = v0.y; w[2]  = v0.z; w[3]  = v0.w;
        w[4]  = v1.x; w[5]  = v1.y; w[6]  = v1.z; w[7]  = v1.w;
        w[8]  = v2.x; w[9]  = v2.y; w[10] = v2.z; w[11] = v2.w;
        w[12] = v3.x; w[13] = v3.y; w[14] = v3.z; w[15] = v3.w;
    }
}

// SWIZZLED LDS window load: 16 floats at region-relative offsets foff..foff+15
// (foff multiple of 4, >= 0). base = region origin (32-float aligned).
__device__ __forceinline__ void lw16s(const float* __restrict__ base, int foff, float* w) {
#pragma unroll
    for (int j = 0; j < 4; ++j) {
        const float4 v = *(const float4*)(base + swz4(foff + 4 * j));
        w[4*j+0] = v.x; w[4*j+1] = v.y; w[4*j+2] = v.z; w[4*j+3] = v.w;
    }
}
// Reflect path (global q==0, only on h==0 where the region shift is 0).
__device__ __forceinline__ void lw16s_q0(const float* __restrict__ base, float* w) {
#pragma unroll
    for (int i = 0; i < 16; ++i) { int m = i - 8; m = (m < 0) ? -m : m; w[i] = base[swz1(m)]; }
}

__device__ __forceinline__ void ntst4(float* p, float a0, float a1, float a2, float a3) {
    f32x4 v; v.x = a0; v.y = a1; v.z = a2; v.w = a3;
    __builtin_nontemporal_store(v, (f32x4*)p);
}

// Barrier that waits on LDS ops only; outstanding global (NT) stores keep
// draining in the background.
__device__ __forceinline__ void barrier_lds() {
    asm volatile("s_waitcnt lgkmcnt(0)" ::: "memory");
    __builtin_amdgcn_s_barrier();
    asm volatile("" ::: "memory");
}

__global__ __launch_bounds__(256, 8)
void dwt5_kernel(const float* __restrict__ x, float* __restrict__ out)
{
    // Region map (floats; origins 32-float aligned; extents swizzle-safe):
    //   a1: buf+0    [0 .. 2176)
    //   a2: buf+2176 [0 .. 1088)   REG2  (live with a1 during L2)
    //   a3: buf+0    [0 .. 544)    (overwrites dead a1 after barrier)
    //   a4: buf+1024 [0 .. 272)    REG4  (disjoint from a3)
    __shared__ float buf[3264];   // 12.75 KB -> 8 blocks/CU (thread-capped)
    const int bid = blockIdx.x;
    const int r   = bid >> 2;     // row
    const int h   = bid & 3;      // quarter
    const int tid = threadIdx.x;

    const float* __restrict__ xr = x + (size_t)r * SLEN;
    const size_t frBase = (size_t)33554432 + (size_t)r * 8192;

    // Region shift per level (quarter h=0 has no halo).
    const int A1s = h ? 2048*h - 120 : 0;
    const int A2s = h ? 1024*h - 56  : 0;
    const int A3s = h ?  512*h - 24  : 0;
    const int A4s = h ?  256*h - 8   : 0;
    constexpr int REG2 = 2176;
    constexpr int REG4 = 1024;

    // ---- L1: x -> a1 (low only; d1 never output) ----
    {
        const int g1lo = A1s >> 2;            // 512h-30 | 0
        const int g1hi = 512 * (h + 1);
#pragma unroll
        for (int jj = 0; jj < 3; ++jj) {
            const int g = g1lo + tid + jj * 256;
            if (g < g1hi) {
                float w[16];
                loadw16g(xr, g, w);
                const float a0 = dotH(w + 1), a1 = dotH(w + 3), a2 = dotH(w + 5), a3 = dotH(w + 7);
                *(float4*)(buf + swz4(4 * g - A1s)) = make_float4(a0, a1, a2, a3);
            }
        }
    }
    barrier_lds();

    // ---- L2: a1 -> a2 (REG2), d2 -> Fg + FR ----
    {
        const int g2lo = A2s >> 2;            // 256h-14 | 0
        const int g2hi = 256 * (h + 1);
        const int gd   = 256 * h;
        float* __restrict__ hi1 = out + (size_t)16777216 + (size_t)r * 4096;
        float* __restrict__ hi2 = out + frBase + 4096;
#pragma unroll
        for (int jj = 0; jj < 2; ++jj) {
            const int g = g2lo + tid + jj * 256;
            if (g < g2hi) {
                float w[16];
                if (g == 0) lw16s_q0(buf, w);
                else        lw16s(buf, 8 * g - 8 - A1s, w);
                const float a0 = dotH(w + 1), a1 = dotH(w + 3), a2 = dotH(w + 5), a3 = dotH(w + 7);
                *(float4*)(buf + REG2 + swz4(4 * g - A2s)) = make_float4(a0, a1, a2, a3);
                if (g >= gd) {
                    const float d0 = dotG(w + 1), d1 = dotG(w + 3), d2 = dotG(w + 5), d3 = dotG(w + 7);
                    ntst4(hi1 + 4 * g, d0, d1, d2, d3);
                    ntst4(hi2 + 4 * g, d0, d1, d2, d3);
                }
            }
        }
    }
    barrier_lds();

    // ---- L3: a2 -> a3 (into dead a1 area), d3 -> Fb + FR ----
    {
        const int g3lo = A3s >> 2;            // 128h-6 | 0
        const int g3hi = 128 * (h + 1);
        const int gd   = 128 * h;
        float* __restrict__ hi1 = out + (size_t)8388608 + (size_t)r * 2048;
        float* __restrict__ hi2 = out + frBase + 2048;
        const int g = g3lo + tid;
        if (g < g3hi) {
            float w[16];
            if (g == 0) lw16s_q0(buf + REG2, w);
            else        lw16s(buf + REG2, 8 * g - 8 - A2s, w);
            const float a0 = dotH(w + 1), a1 = dotH(w + 3), a2 = dotH(w + 5), a3 = dotH(w + 7);
            *(float4*)(buf + swz4(4 * g - A3s)) = make_float4(a0, a1, a2, a3);
            if (g >= gd) {
                const float d0 = dotG(w + 1), d1 = dotG(w + 3), d2 = dotG(w + 5), d3 = dotG(w + 7);
                ntst4(hi1 + 4 * g, d0, d1, d2, d3);
                ntst4(hi2 + 4 * g, d0, d1, d2, d3);
            }
        }
    }
    barrier_lds();

    // ---- L4: a3 -> a4 (REG4), d4 -> Fa + FR ----
    {
        const int g4lo = A4s >> 2;            // 64h-2 | 0
        const int g4hi = 64 * (h + 1);
        const int gd   = 64 * h;
        float* __restrict__ hi1 = out + (size_t)4194304 + (size_t)r * 1024;
        float* __restrict__ hi2 = out + frBase + 1024;
        const int g = g4lo + tid;
        if (g < g4hi) {
            float w[16];
            if (g == 0) lw16s_q0(buf, w);
            else        lw16s(buf, 8 * g - 8 - A3s, w);
            const float a0 = dotH(w + 1), a1 = dotH(w + 3), a2 = dotH(w + 5), a3 = dotH(w + 7);
            *(float4*)(buf + REG4 + swz4(4 * g - A4s)) = make_float4(a0, a1, a2, a3);
            if (g >= gd) {
                const float d0 = dotG(w + 1), d1 = dotG(w + 3), d2 = dotG(w + 5), d3 = dotG(w + 7);
                ntst4(hi1 + 4 * g, d0, d1, d2, d3);
                ntst4(hi2 + 4 * g, d0, d1, d2, d3);
            }
        }
    }
    barrier_lds();

    // ---- L5: a4 -> Fd + Ft, both also to FR ----
    if (tid < 32) {
        const int g = 32 * h + tid;
        float w[16];
        if (g == 0) lw16s_q0(buf + REG4, w);
        else        lw16s(buf + REG4, 8 * g - 8 - A4s, w);
        const float a0 = dotH(w + 1), a1 = dotH(w + 3), a2 = dotH(w + 5), a3 = dotH(w + 7);
        const float d0 = dotG(w + 1), d1 = dotG(w + 3), d2 = dotG(w + 5), d3 = dotG(w + 7);
        ntst4(out + (size_t)r * 512 + 4 * g,                   a0, a1, a2, a3);
        ntst4(out + frBase + 4 * g,                            a0, a1, a2, a3);
        ntst4(out + (size_t)2097152 + (size_t)r * 512 + 4 * g, d0, d1, d2, d3);
        ntst4(out + frBase + 512 + 4 * g,                      d0, d1, d2, d3);
    }
}

extern "C" void kernel_launch(void* const* d_in, const int* in_sizes, int n_in,
                              void* d_out, int out_size, void* d_ws, size_t ws_size,
                              hipStream_t stream) {
    const float* x = (const float*)d_in[0];
    float* out = (float*)d_out;
    dwt5_kernel<<<16384, 256, 0, stream>>>(x, out);
}